// Round 1
// baseline (375.198 us; speedup 1.0000x reference)
//
#include <hip/hip_runtime.h>

// Pooling_87239375716838: sliding-window 4-point FFT pooling (real part).
// x: [1, T=131072, D=128] f32.
// For each i: window rows start..start+3, start = max(0, i-1);
// tap j valid iff (start+j < i+3) && (start+j < T).
//   i == 0 -> start 0, taps {0,1,2} valid (3 valid)
//   i >= 1 -> start i-1, all taps < i+3, valid count = min(4, T-(i-1))
// FFT4 real parts of (w0,w1,w2,w3):
//   X0 = w0+w1+w2+w3 ; X1 = w0-w2 ; X2 = w0-w1+w2-w3 ; X3 = w0-w2
// coarse = mean(X0..X3) = w0.
// Output layout (concat flat): coarse [T*128] then fine [T*512].

__global__ __launch_bounds__(256) void pool_fft_kernel(
    const float* __restrict__ x,
    float* __restrict__ coarse,
    float* __restrict__ fine,
    int T) {
    const int gtid = blockIdx.x * blockDim.x + threadIdx.x;
    const int lane = gtid & 31;   // float4 slot within D=128 (32 * 4 = 128)
    const int i = gtid >> 5;      // row index
    if (i >= T) return;
    const int d4 = lane << 2;

    const int start = (i == 0) ? 0 : (i - 1);
    const int nvalid = (i == 0) ? 3 : min(4, T - start);

    float4 w0 = make_float4(0.f, 0.f, 0.f, 0.f);
    float4 w1 = w0, w2 = w0, w3 = w0;

    const float* base = x + (size_t)start * 128 + d4;
    // nvalid >= 2 always (T >= 2): taps 0 and 1 unconditional
    w0 = *reinterpret_cast<const float4*>(base);
    w1 = *reinterpret_cast<const float4*>(base + 128);
    if (nvalid > 2) w2 = *reinterpret_cast<const float4*>(base + 256);
    if (nvalid > 3) w3 = *reinterpret_cast<const float4*>(base + 384);

    // coarse = w0
    *reinterpret_cast<float4*>(&coarse[(size_t)i * 128 + d4]) = w0;

    float4 f0, f1, f2;
    f0.x = w0.x + w1.x + w2.x + w3.x;
    f0.y = w0.y + w1.y + w2.y + w3.y;
    f0.z = w0.z + w1.z + w2.z + w3.z;
    f0.w = w0.w + w1.w + w2.w + w3.w;
    f1.x = w0.x - w2.x;
    f1.y = w0.y - w2.y;
    f1.z = w0.z - w2.z;
    f1.w = w0.w - w2.w;
    f2.x = w0.x - w1.x + w2.x - w3.x;
    f2.y = w0.y - w1.y + w2.y - w3.y;
    f2.z = w0.z - w1.z + w2.z - w3.z;
    f2.w = w0.w - w1.w + w2.w - w3.w;

    float* fb = fine + (size_t)i * 512 + d4;
    *reinterpret_cast<float4*>(fb)       = f0;
    *reinterpret_cast<float4*>(fb + 128) = f1;
    *reinterpret_cast<float4*>(fb + 256) = f2;
    *reinterpret_cast<float4*>(fb + 384) = f1;
}

extern "C" void kernel_launch(void* const* d_in, const int* in_sizes, int n_in,
                              void* d_out, int out_size, void* d_ws, size_t ws_size,
                              hipStream_t stream) {
    const float* x = (const float*)d_in[0];
    const int D = 128;
    const int T = in_sizes[0] / D;            // 131072
    float* coarse = (float*)d_out;            // T*128
    float* fine = (float*)d_out + (size_t)T * D;  // T*512

    const int threads_per_row = D / 4;        // 32
    const long long total = (long long)T * threads_per_row;
    const int block = 256;
    const int grid = (int)((total + block - 1) / block);
    pool_fft_kernel<<<grid, block, 0, stream>>>(x, coarse, fine, T);
}

// Round 7
// 366.193 us; speedup vs baseline: 1.0246x; 1.0246x over previous
//
#include <hip/hip_runtime.h>

// Pooling_87239375716838: sliding-window 4-point FFT pooling (real part).
// x: [1, T=131072, D=128] f32.
// Window for position i: rows start..start+3, start = max(0, i-1);
// tap j valid iff (start+j < i+3) && (start+j < T).
// FFT4 real parts of (w0..w3): X0=w0+w1+w2+w3; X1=X3=w0-w2; X2=w0-w1+w2-w3.
// coarse = mean(X0..X3) = w0.
// Output: coarse [T*128] then fine [T*512], concatenated flat.
//
// v2b: two adjacent rows per thread (windows i,i+1 share taps -> 5 loads,
// 10 stores), branchless tail masking, nontemporal stores via native clang
// ext_vector_type (HIP's float4 class is rejected by the builtin).

typedef float f4 __attribute__((ext_vector_type(4)));

__device__ __forceinline__ f4 ldf4(const float* p) {
    return *reinterpret_cast<const f4*>(p);
}

__device__ __forceinline__ void emit_window(
    float* __restrict__ coarse, float* __restrict__ fine,
    long long i, int d4,
    f4 w0, f4 w1, f4 w2, f4 w3) {
    f4 f0 = w0 + w1 + w2 + w3;
    f4 f1 = w0 - w2;
    f4 f2 = w0 - w1 + w2 - w3;
    __builtin_nontemporal_store(w0, reinterpret_cast<f4*>(coarse + i * 128 + d4));
    float* fb = fine + i * 512 + d4;
    __builtin_nontemporal_store(f0, reinterpret_cast<f4*>(fb));
    __builtin_nontemporal_store(f1, reinterpret_cast<f4*>(fb + 128));
    __builtin_nontemporal_store(f2, reinterpret_cast<f4*>(fb + 256));
    __builtin_nontemporal_store(f1, reinterpret_cast<f4*>(fb + 384));
}

__global__ __launch_bounds__(256) void pool_fft2_kernel(
    const float* __restrict__ x,
    float* __restrict__ coarse,
    float* __restrict__ fine,
    int T) {
    const int gtid = blockIdx.x * blockDim.x + threadIdx.x;
    const int lane = gtid & 31;          // float4 slot within D=128
    const int p = gtid >> 5;             // row pair index
    const int P = T >> 1;
    if (p >= P) return;
    const int i0 = p << 1;
    const int d4 = lane << 2;
    const f4 Z = {0.f, 0.f, 0.f, 0.f};

    if (i0 == 0) {
        // i=0: taps rows {0,1,2}, pad; i=1: taps rows {0,1,2,3}
        const float* b = x + d4;
        f4 A  = ldf4(b);
        f4 B  = ldf4(b + 128);
        f4 C  = ldf4(b + 256);
        f4 Dv = ldf4(b + 384);
        emit_window(coarse, fine, 0, d4, A, B, C, Z);
        emit_window(coarse, fine, 1, d4, A, B, C, Dv);
    } else {
        // rows i0-1 .. i0+3; only i0+2, i0+3 can exceed T-1
        const float* b = x + (size_t)(i0 - 1) * 128 + d4;
        f4 L0 = ldf4(b);
        f4 L1 = ldf4(b + 128);
        f4 L2 = ldf4(b + 256);
        const int r3 = min(i0 + 2, T - 1);
        const int r4 = min(i0 + 3, T - 1);
        f4 L3 = ldf4(x + (size_t)r3 * 128 + d4);
        f4 L4 = ldf4(x + (size_t)r4 * 128 + d4);
        if (i0 + 2 >= T) L3 = Z;   // wave-uniform predicate, cheap select
        if (i0 + 3 >= T) L4 = Z;
        emit_window(coarse, fine, i0,     d4, L0, L1, L2, L3);
        emit_window(coarse, fine, i0 + 1, d4, L1, L2, L3, L4);
    }
}

extern "C" void kernel_launch(void* const* d_in, const int* in_sizes, int n_in,
                              void* d_out, int out_size, void* d_ws, size_t ws_size,
                              hipStream_t stream) {
    const float* x = (const float*)d_in[0];
    const int D = 128;
    const int T = in_sizes[0] / D;                 // 131072
    float* coarse = (float*)d_out;                 // T*128
    float* fine = (float*)d_out + (size_t)T * D;   // T*512

    const long long pairs = T / 2;
    const long long total = pairs * 32;            // 32 lanes per row pair
    const int block = 256;
    const int grid = (int)((total + block - 1) / block);
    pool_fft2_kernel<<<grid, block, 0, stream>>>(x, coarse, fine, T);
}

// Round 10
// 363.075 us; speedup vs baseline: 1.0334x; 1.0086x over previous
//
#include <hip/hip_runtime.h>

// Pooling_87239375716838: sliding-window 4-point FFT pooling (real part).
// x: [1, T=131072, D=128] f32.
// Window for position i: start = max(0, i-1); taps x[start..start+3],
// tap valid iff row < i+3 && row < T (invalid -> zero pad).
// FFT4 real parts: X0=w0+w1+w2+w3; X1=X3=w0-w2; X2=w0-w1+w2-w3.
// coarse[i] = mean(X0..X3) = w0 = x[max(0,i-1)].
// Output: coarse [T*128] then fine [T*512], concatenated flat.
//
// v3: one wave owns 4 rows. half-wave 0 (lanes 0-31) produces X0/X2,
// half-wave 1 (lanes 32-63) produces X1 (== X3); both halves load the same
// 7 tap rows (same-address loads coalesce). Every store instruction is one
// fully contiguous 1 KiB segment:
//   fine row i:  [slot0|slot1] then [slot2|slot3]   (2 stores/row)
//   coarse:      rows (r0,r0+1) then (r0+2,r0+3)    (2 stores/4 rows)
// All output nontemporal (write-once, keep x L3-resident).

typedef float f4 __attribute__((ext_vector_type(4)));

__device__ __forceinline__ f4 ldf4(const float* p) {
    return *reinterpret_cast<const f4*>(p);
}

__global__ __launch_bounds__(256) void pool_fft4_kernel(
    const float* __restrict__ x,
    float* __restrict__ coarse,
    float* __restrict__ fine,
    int T) {
    const int wv   = threadIdx.x >> 6;   // wave within block (0..3)
    const int lane = threadIdx.x & 63;
    const int half = lane >> 5;          // 0: X0/X2 producer, 1: X1/X3
    const int c    = lane & 31;          // float4 chunk within D=128
    const int d4   = c << 2;
    const int r0   = (blockIdx.x * 4 + wv) * 4;  // first of this wave's 4 rows
    if (r0 >= T) return;

    const f4 Z = {0.f, 0.f, 0.f, 0.f};

    // taps: rows r0-1 .. r0+5 (clamped addresses, masked past T)
    f4 t[7];
#pragma unroll
    for (int k = 0; k < 7; ++k) {
        const int row = r0 - 1 + k;
        const int rc  = min(max(row, 0), T - 1);
        const f4 v = ldf4(x + (size_t)rc * 128 + d4);
        t[k] = (row >= T) ? Z : v;
    }

    // coarse: w0 of each window; two contiguous 1 KiB stores
    {
        const f4 cA = half ? t[1] : ((r0 == 0) ? t[1] : t[0]);
        const f4 cB = half ? t[3] : t[2];
        __builtin_nontemporal_store(
            cA, reinterpret_cast<f4*>(coarse + (size_t)(r0 + half) * 128 + d4));
        __builtin_nontemporal_store(
            cB, reinterpret_cast<f4*>(coarse + (size_t)(r0 + 2 + half) * 128 + d4));
    }

#pragma unroll
    for (int q = 0; q < 4; ++q) {
        const int i = r0 + q;
        f4 w0 = t[q], w1 = t[q + 1], w2 = t[q + 2], w3 = t[q + 3];
        if (q == 0 && r0 == 0) {   // window 0: taps rows {0,1,2}, zero pad
            w0 = t[1]; w1 = t[2]; w2 = t[3]; w3 = Z;
        }
        const f4 f1 = w0 - w2;                       // X1 == X3
        const f4 vA = half ? f1 : (w0 + w1 + w2 + w3);   // slot0|slot1
        const f4 vB = half ? f1 : (w0 - w1 + w2 - w3);   // slot2|slot3
        float* fb = fine + (size_t)i * 512 + half * 128 + d4;
        __builtin_nontemporal_store(vA, reinterpret_cast<f4*>(fb));
        __builtin_nontemporal_store(vB, reinterpret_cast<f4*>(fb + 256));
    }
}

extern "C" void kernel_launch(void* const* d_in, const int* in_sizes, int n_in,
                              void* d_out, int out_size, void* d_ws, size_t ws_size,
                              hipStream_t stream) {
    const float* x = (const float*)d_in[0];
    const int D = 128;
    const int T = in_sizes[0] / D;                 // 131072
    float* coarse = (float*)d_out;                 // T*128
    float* fine = (float*)d_out + (size_t)T * D;   // T*512

    const int rows_per_block = 16;                 // 4 waves x 4 rows
    const int grid = (T + rows_per_block - 1) / rows_per_block;
    pool_fft4_kernel<<<grid, 256, 0, stream>>>(x, coarse, fine, T);
}